// Round 1
// baseline (2584.720 us; speedup 1.0000x reference)
//
#include <hip/hip_runtime.h>
#include <math.h>

#define G   200
#define G2  40000
#define NPT 128

// float-space constants (match f32 arithmetic of the reference)
__device__ __forceinline__ float f_min_lon() { return 95.987f; }
__device__ __forceinline__ float f_min_lat() { return 31.3039f; }
__device__ __forceinline__ float f_dlon()    { return (float)((109.4132 - 95.987) / 200.0); }
__device__ __forceinline__ float f_dlat()    { return (float)((42.879 - 31.3039) / 200.0); }
__device__ __forceinline__ float f_rad()     { return 0.017453292519943295f; } // pi/180 -> f32

// workspace float layout (after 16-byte header holding the atomic key)
#define W1A_OFF  0        // 32  : w1[0][k] * a1[k]
#define B2F_OFF  32       // 32  : folded layer-2 bias
#define W2F_OFF  64       // 1024: w2[k][j] * a2[j]
#define W3_OFF   1088     // 160 : w3 copy
#define B3_OFF   1248     // 5 (pad to 8)
#define PERN_OFF 1256     // 128*8: {sin(lat2), cos(lat2), lon2rad, tim, rid, pad...}
#define C_OFF    2280     // 128*32: per-n folded layer-1 constant
#define WS_FLOATS 6376

__global__ void setup_kernel(const float* __restrict__ x,
                             const float* __restrict__ w1, const float* __restrict__ b1,
                             const float* __restrict__ g1, const float* __restrict__ be1,
                             const float* __restrict__ m1, const float* __restrict__ v1,
                             const float* __restrict__ w2, const float* __restrict__ b2,
                             const float* __restrict__ g2, const float* __restrict__ be2,
                             const float* __restrict__ m2, const float* __restrict__ v2,
                             const float* __restrict__ w3, const float* __restrict__ b3,
                             float* __restrict__ wsf)
{
    const int t = threadIdx.x; // 256 threads, 1 block
    // folded layer-2 weights
    for (int idx = t; idx < 1024; idx += 256) {
        int j = idx & 31;
        float a2 = g2[j] / sqrtf(v2[j] + 1e-5f);
        wsf[W2F_OFF + idx] = w2[idx] * a2;
    }
    if (t < 32) {
        float a1 = g1[t] / sqrtf(v1[t] + 1e-5f);
        wsf[W1A_OFF + t] = w1[t] * a1;                      // w1[0][t] folded
        float a2 = g2[t] / sqrtf(v2[t] + 1e-5f);
        wsf[B2F_OFF + t] = (b2[t] - m2[t]) * a2 + be2[t];
    }
    for (int idx = t; idx < 160; idx += 256) wsf[W3_OFF + idx] = w3[idx];
    if (t < 5) wsf[B3_OFF + t] = b3[t];
    if (t < NPT) {
        float lon = x[t * 4 + 0], lat = x[t * 4 + 1];
        float tim = x[t * 4 + 2], rid = x[t * 4 + 3];
        float lat2 = lat * f_rad();
        wsf[PERN_OFF + t * 8 + 0] = sinf(lat2);
        wsf[PERN_OFF + t * 8 + 1] = cosf(lat2);
        wsf[PERN_OFF + t * 8 + 2] = lon * f_rad();
        wsf[PERN_OFF + t * 8 + 3] = tim;
        wsf[PERN_OFF + t * 8 + 4] = rid;
        wsf[PERN_OFF + t * 8 + 5] = 0.0f;
        wsf[PERN_OFF + t * 8 + 6] = 0.0f;
        wsf[PERN_OFF + t * 8 + 7] = 0.0f;
    }
    // per-n folded layer-1 constants: ((tim/100)*w1[1][k] + b1[k] - m1[k])*a1[k] + be1[k]
    for (int idx = t; idx < NPT * 32; idx += 256) {
        int n = idx >> 5, k = idx & 31;
        float a1 = g1[k] / sqrtf(v1[k] + 1e-5f);
        float tim = x[n * 4 + 2];
        wsf[C_OFF + idx] = ((tim / 100.0f) * w1[32 + k] + b1[k] - m1[k]) * a1 + be1[k];
    }
}

// per-(grid i, point n) classification; returns predicted class and distance (km)
__device__ __forceinline__ void compute_pair(int i, int n, const float* __restrict__ wsf,
                                             int& pid, float& gd_out)
{
    int gi = i / G;
    int gj = i - gi * G;
    float glon = f_min_lon() + f_dlon() * (float)gj;
    float glat = f_min_lat() + f_dlat() * (float)gi;
    float lat1 = glat * f_rad();
    float lon1 = glon * f_rad();
    float s1 = sinf(lat1), c1 = cosf(lat1);

    const float* pn = wsf + PERN_OFF + n * 8;
    float slat2 = pn[0], clat2 = pn[1], lon2 = pn[2];

    float dl  = lon2 - lon1;
    float sdl = sinf(dl), cdl = cosf(dl);
    float A = clat2 * sdl;
    float B = c1 * slat2 - s1 * clat2 * cdl;
    float numer = sqrtf(A * A + B * B);
    float denom = s1 * slat2 + c1 * clat2 * cdl;
    float gd = atan2f(numer, denom) * 6371.0f;
    float u = gd / 100.0f;

    // layer 1: h1[k] = tanh(u * W1a[k] + C[n][k])
    float h1[32];
#pragma unroll
    for (int k = 0; k < 32; k++)
        h1[k] = tanhf(u * wsf[W1A_OFF + k] + wsf[C_OFF + n * 32 + k]);

    // layer 2: 32x32
    float acc[32];
#pragma unroll
    for (int j = 0; j < 32; j++) acc[j] = wsf[B2F_OFF + j];
#pragma unroll
    for (int k = 0; k < 32; k++) {
        float hk = h1[k];
#pragma unroll
        for (int j = 0; j < 32; j++)
            acc[j] = fmaf(hk, wsf[W2F_OFF + k * 32 + j], acc[j]);
    }

    // layer 3: 32x5 with tanh applied on the fly
    float lg[5];
#pragma unroll
    for (int c = 0; c < 5; c++) lg[c] = wsf[B3_OFF + c];
#pragma unroll
    for (int j = 0; j < 32; j++) {
        float h2 = tanhf(acc[j]);
#pragma unroll
        for (int c = 0; c < 5; c++)
            lg[c] = fmaf(h2, wsf[W3_OFF + j * 5 + c], lg[c]);
    }

    int best = 0;
    float bv = lg[0];
#pragma unroll
    for (int c = 1; c < 5; c++)
        if (lg[c] > bv) { bv = lg[c]; best = c; } // strict > keeps first-occurrence ties
    pid = best;
    gd_out = gd;
}

__global__ __launch_bounds__(NPT) void pass1_kernel(const float* __restrict__ wsf,
                                                    unsigned* __restrict__ key)
{
    const int i = blockIdx.x;
    const int n = threadIdx.x;
    int pid; float gd;
    compute_pair(i, n, wsf, pid, gd);
    float rid = wsf[PERN_OFF + n * 8 + 4];
    bool match = ((float)pid == rid);
    unsigned long long m = __ballot(match);
    int cnt = __popcll(m);
    __shared__ int s[2];
    if ((n & 63) == 0) s[n >> 6] = cnt;
    __syncthreads();
    if (n == 0) {
        int num = s[0] + s[1];
        unsigned k = ((unsigned)num << 16) | (unsigned)(G2 - 1 - i);
        atomicMax(key, k);
    }
}

__global__ __launch_bounds__(NPT) void pass2_kernel(const float* __restrict__ wsf,
                                                    const unsigned* __restrict__ key,
                                                    float* __restrict__ out)
{
    unsigned k = *key;
    int i = (G2 - 1) - (int)(k & 0xFFFFu);
    int num = (int)(k >> 16);
    const int n = threadIdx.x;
    int pid; float gd;
    compute_pair(i, n, wsf, pid, gd);
    out[n] = (float)pid;                                  // class_
    float tim = wsf[PERN_OFF + n * 8 + 3];
    out[NPT + 2 * n + 0] = (gd / 100.0f) * 100.0f;        // ph[:,0] (match ref rounding)
    out[NPT + 2 * n + 1] = (tim / 100.0f) * 100.0f;       // ph[:,1]
    if (n == 0) {
        out[3 * NPT] = (float)num;                        // max(num)
        int gi = i / G, gj = i - gi * G;
        out[3 * NPT + 1] = f_min_lon() + f_dlon() * (float)gj;  // pos lon
        out[3 * NPT + 2] = f_min_lat() + f_dlat() * (float)gi;  // pos lat
    }
}

extern "C" void kernel_launch(void* const* d_in, const int* in_sizes, int n_in,
                              void* d_out, int out_size, void* d_ws, size_t ws_size,
                              hipStream_t stream)
{
    const float* x   = (const float*)d_in[0];
    const float* w1  = (const float*)d_in[1];
    const float* b1  = (const float*)d_in[2];
    const float* g1  = (const float*)d_in[3];
    const float* be1 = (const float*)d_in[4];
    const float* m1  = (const float*)d_in[5];
    const float* v1  = (const float*)d_in[6];
    const float* w2  = (const float*)d_in[7];
    const float* b2  = (const float*)d_in[8];
    const float* g2  = (const float*)d_in[9];
    const float* be2 = (const float*)d_in[10];
    const float* m2  = (const float*)d_in[11];
    const float* v2  = (const float*)d_in[12];
    const float* w3  = (const float*)d_in[13];
    const float* b3  = (const float*)d_in[14];

    unsigned* key = (unsigned*)d_ws;
    float* wsf = (float*)((char*)d_ws + 16);

    hipMemsetAsync(d_ws, 0, 16, stream);
    setup_kernel<<<1, 256, 0, stream>>>(x, w1, b1, g1, be1, m1, v1,
                                        w2, b2, g2, be2, m2, v2, w3, b3, wsf);
    pass1_kernel<<<G2, NPT, 0, stream>>>(wsf, key);
    pass2_kernel<<<1, NPT, 0, stream>>>(wsf, key, (float*)d_out);
}

// Round 2
// 1289.066 us; speedup vs baseline: 2.0051x; 2.0051x over previous
//
#include <hip/hip_runtime.h>
#include <math.h>

#define G   200
#define G2  40000
#define NPT 128

// float-space constants (match f32 arithmetic of the reference)
__device__ __forceinline__ float f_min_lon() { return 95.987f; }
__device__ __forceinline__ float f_min_lat() { return 31.3039f; }
__device__ __forceinline__ float f_dlon()    { return (float)((109.4132 - 95.987) / 200.0); }
__device__ __forceinline__ float f_dlat()    { return (float)((42.879 - 31.3039) / 200.0); }
__device__ __forceinline__ float f_rad()     { return 0.017453292519943295f; } // pi/180 -> f32

// workspace float layout (after 16-byte header holding the atomic key)
// All float4-accessed regions are 16B-aligned (offsets in floats, multiples of 4; d_ws+16 keeps 16B alignment).
#define W1A_OFF  0        // 32  : w1[0][k] * a1[k]
#define B2F_OFF  32       // 32  : folded layer-2 bias
#define W2F_OFF  64       // 1024: w2[k][j] * a2[j]
#define W3_OFF   1088     // 160 : w3 copy
#define B3_OFF   1248     // 5 (pad to 8)
#define PERN_OFF 1256     // 128*8: {sin(lat2), cos(lat2), lon2rad, tim, rid, pad...}
#define C_OFF    2280     // 128*32: per-n folded layer-1 constant (C_OFF*4 = 9120 B, 16B-aligned)
#define WS_FLOATS 6376

__global__ void setup_kernel(const float* __restrict__ x,
                             const float* __restrict__ w1, const float* __restrict__ b1,
                             const float* __restrict__ g1, const float* __restrict__ be1,
                             const float* __restrict__ m1, const float* __restrict__ v1,
                             const float* __restrict__ w2, const float* __restrict__ b2,
                             const float* __restrict__ g2, const float* __restrict__ be2,
                             const float* __restrict__ m2, const float* __restrict__ v2,
                             const float* __restrict__ w3, const float* __restrict__ b3,
                             float* __restrict__ wsf)
{
    const int t = threadIdx.x; // 256 threads, 1 block
    for (int idx = t; idx < 1024; idx += 256) {
        int j = idx & 31;
        float a2 = g2[j] / sqrtf(v2[j] + 1e-5f);
        wsf[W2F_OFF + idx] = w2[idx] * a2;
    }
    if (t < 32) {
        float a1 = g1[t] / sqrtf(v1[t] + 1e-5f);
        wsf[W1A_OFF + t] = w1[t] * a1;                      // w1[0][t] folded
        float a2 = g2[t] / sqrtf(v2[t] + 1e-5f);
        wsf[B2F_OFF + t] = (b2[t] - m2[t]) * a2 + be2[t];
    }
    for (int idx = t; idx < 160; idx += 256) wsf[W3_OFF + idx] = w3[idx];
    if (t < 8) wsf[B3_OFF + t] = (t < 5) ? b3[t] : 0.0f;
    if (t < NPT) {
        float lon = x[t * 4 + 0], lat = x[t * 4 + 1];
        float tim = x[t * 4 + 2], rid = x[t * 4 + 3];
        float lat2 = lat * f_rad();
        wsf[PERN_OFF + t * 8 + 0] = sinf(lat2);
        wsf[PERN_OFF + t * 8 + 1] = cosf(lat2);
        wsf[PERN_OFF + t * 8 + 2] = lon * f_rad();
        wsf[PERN_OFF + t * 8 + 3] = tim;
        wsf[PERN_OFF + t * 8 + 4] = rid;
        wsf[PERN_OFF + t * 8 + 5] = 0.0f;
        wsf[PERN_OFF + t * 8 + 6] = 0.0f;
        wsf[PERN_OFF + t * 8 + 7] = 0.0f;
    }
    for (int idx = t; idx < NPT * 32; idx += 256) {
        int n = idx >> 5, k = idx & 31;
        float a1 = g1[k] / sqrtf(v1[k] + 1e-5f);
        float tim = x[n * 4 + 2];
        wsf[C_OFF + idx] = ((tim / 100.0f) * w1[32 + k] + b1[k] - m1[k]) * a1 + be1[k];
    }
}

// per-(grid i, point n) classification; register-blocked so peak liveness
// ~45 floats (h1[32] + acc[8] + lg[5]) — no spills, all indices constant.
__device__ __forceinline__ void compute_pair(int i, int n, const float* __restrict__ wsf,
                                             int& pid, float& gd_out)
{
    int gi = i / G;
    int gj = i - gi * G;
    float glon = f_min_lon() + f_dlon() * (float)gj;
    float glat = f_min_lat() + f_dlat() * (float)gi;
    float lat1 = glat * f_rad();
    float lon1 = glon * f_rad();
    float s1 = sinf(lat1), c1 = cosf(lat1);

    const float* pn = wsf + PERN_OFF + n * 8;
    float slat2 = pn[0], clat2 = pn[1], lon2 = pn[2];

    float dl  = lon2 - lon1;
    float sdl = sinf(dl), cdl = cosf(dl);
    float A = clat2 * sdl;
    float B = c1 * slat2 - s1 * clat2 * cdl;
    float numer = sqrtf(A * A + B * B);
    float denom = s1 * slat2 + c1 * clat2 * cdl;
    float gd = atan2f(numer, denom) * 6371.0f;
    float u = gd / 100.0f;

    // layer 1: h1[k] = tanh(fma(u, W1a[k], C[n][k])) — float4 loads, k ascending
    const float4* W1A4 = (const float4*)(wsf + W1A_OFF);
    const float4* C4   = (const float4*)(wsf + C_OFF + n * 32);
    float h1[32];
#pragma unroll
    for (int q = 0; q < 8; q++) {
        float4 wa = W1A4[q];
        float4 cc = C4[q];
        h1[4 * q + 0] = tanhf(fmaf(u, wa.x, cc.x));
        h1[4 * q + 1] = tanhf(fmaf(u, wa.y, cc.y));
        h1[4 * q + 2] = tanhf(fmaf(u, wa.z, cc.z));
        h1[4 * q + 3] = tanhf(fmaf(u, wa.w, cc.w));
    }

    float lg[5];
#pragma unroll
    for (int c = 0; c < 5; c++) lg[c] = wsf[B3_OFF + c];

    // layers 2+3 in 4 groups of 8 output neurons; k-ascending accumulation
    // order matches the previously-passing numerics exactly.
#pragma unroll
    for (int jc = 0; jc < 4; jc++) {
        float acc[8];
        {
            const float4* B2F4 = (const float4*)(wsf + B2F_OFF + jc * 8);
            float4 b0 = B2F4[0], b1v = B2F4[1];
            acc[0] = b0.x;  acc[1] = b0.y;  acc[2] = b0.z;  acc[3] = b0.w;
            acc[4] = b1v.x; acc[5] = b1v.y; acc[6] = b1v.z; acc[7] = b1v.w;
        }
#pragma unroll
        for (int k = 0; k < 32; k++) {
            const float4* W24 = (const float4*)(wsf + W2F_OFF + k * 32 + jc * 8);
            float4 w0 = W24[0], w1v = W24[1];
            float hk = h1[k];
            acc[0] = fmaf(hk, w0.x,  acc[0]);
            acc[1] = fmaf(hk, w0.y,  acc[1]);
            acc[2] = fmaf(hk, w0.z,  acc[2]);
            acc[3] = fmaf(hk, w0.w,  acc[3]);
            acc[4] = fmaf(hk, w1v.x, acc[4]);
            acc[5] = fmaf(hk, w1v.y, acc[5]);
            acc[6] = fmaf(hk, w1v.z, acc[6]);
            acc[7] = fmaf(hk, w1v.w, acc[7]);
        }
#pragma unroll
        for (int m = 0; m < 8; m++) {
            int j = jc * 8 + m;
            float h2 = tanhf(acc[m]);
#pragma unroll
            for (int c = 0; c < 5; c++)
                lg[c] = fmaf(h2, wsf[W3_OFF + j * 5 + c], lg[c]);
        }
    }

    int best = 0;
    float bv = lg[0];
#pragma unroll
    for (int c = 1; c < 5; c++)
        if (lg[c] > bv) { bv = lg[c]; best = c; } // strict > keeps first-occurrence ties
    pid = best;
    gd_out = gd;
}

__global__ __launch_bounds__(NPT) void pass1_kernel(const float* __restrict__ wsf,
                                                    unsigned* __restrict__ key)
{
    const int i = blockIdx.x;
    const int n = threadIdx.x;
    int pid; float gd;
    compute_pair(i, n, wsf, pid, gd);
    float rid = wsf[PERN_OFF + n * 8 + 4];
    bool match = ((float)pid == rid);
    unsigned long long m = __ballot(match);
    int cnt = __popcll(m);
    __shared__ int s[2];
    if ((n & 63) == 0) s[n >> 6] = cnt;
    __syncthreads();
    if (n == 0) {
        int num = s[0] + s[1];
        unsigned k = ((unsigned)num << 16) | (unsigned)(G2 - 1 - i);
        atomicMax(key, k);
    }
}

__global__ __launch_bounds__(NPT) void pass2_kernel(const float* __restrict__ wsf,
                                                    const unsigned* __restrict__ key,
                                                    float* __restrict__ out)
{
    unsigned k = *key;
    int i = (G2 - 1) - (int)(k & 0xFFFFu);
    int num = (int)(k >> 16);
    const int n = threadIdx.x;
    int pid; float gd;
    compute_pair(i, n, wsf, pid, gd);
    out[n] = (float)pid;                                  // class_
    float tim = wsf[PERN_OFF + n * 8 + 3];
    out[NPT + 2 * n + 0] = (gd / 100.0f) * 100.0f;        // ph[:,0] (match ref rounding)
    out[NPT + 2 * n + 1] = (tim / 100.0f) * 100.0f;       // ph[:,1]
    if (n == 0) {
        out[3 * NPT] = (float)num;                        // max(num)
        int gi = i / G, gj = i - gi * G;
        out[3 * NPT + 1] = f_min_lon() + f_dlon() * (float)gj;  // pos lon
        out[3 * NPT + 2] = f_min_lat() + f_dlat() * (float)gi;  // pos lat
    }
}

extern "C" void kernel_launch(void* const* d_in, const int* in_sizes, int n_in,
                              void* d_out, int out_size, void* d_ws, size_t ws_size,
                              hipStream_t stream)
{
    const float* x   = (const float*)d_in[0];
    const float* w1  = (const float*)d_in[1];
    const float* b1  = (const float*)d_in[2];
    const float* g1  = (const float*)d_in[3];
    const float* be1 = (const float*)d_in[4];
    const float* m1  = (const float*)d_in[5];
    const float* v1  = (const float*)d_in[6];
    const float* w2  = (const float*)d_in[7];
    const float* b2  = (const float*)d_in[8];
    const float* g2  = (const float*)d_in[9];
    const float* be2 = (const float*)d_in[10];
    const float* m2  = (const float*)d_in[11];
    const float* v2  = (const float*)d_in[12];
    const float* w3  = (const float*)d_in[13];
    const float* b3  = (const float*)d_in[14];

    unsigned* key = (unsigned*)d_ws;
    float* wsf = (float*)((char*)d_ws + 16);

    hipMemsetAsync(d_ws, 0, 16, stream);
    setup_kernel<<<1, 256, 0, stream>>>(x, w1, b1, g1, be1, m1, v1,
                                        w2, b2, g2, be2, m2, v2, w3, b3, wsf);
    pass1_kernel<<<G2, NPT, 0, stream>>>(wsf, key);
    pass2_kernel<<<1, NPT, 0, stream>>>(wsf, key, (float*)d_out);
}